// Round 11
// baseline (147.628 us; speedup 1.0000x reference)
//
#include <hip/hip_runtime.h>
#include <hip/hip_bf16.h>
#include <stdint.h>

typedef __bf16 bf16x8 __attribute__((ext_vector_type(8)));
typedef float  f32x4  __attribute__((ext_vector_type(4)));

// Weights pre-swizzled into MFMA B-fragment order:
//  slot = (ktile * NF + nfrag); value j of lane l = W[ktile*32 + (l>>4)*8 + j][nfrag*16 + (l&15)]
// Layer 1: K=800 (784 + zero pad), N=512 (500 + pad), 25 k-tiles, 32 n-frags
// Layer 2: K=512 (500 + pad), N=256 (200 + pad), 16 k-tiles, 16 n-frags
// Layer 3: K=256 (200 + pad), N=16 (10 + pad),   8 k-tiles,  1 n-frag
// h1f (workspace): layer-1 output in MFMA-A-fragment order:
//  slot = rowtile*16 + ktile; 16B of lane l = h1[rowtile*16 + (l&15)][kt*32 + (l>>4)*8 ..+8)

#define KT1 25
#define NF1 32
#define KT2 16
#define NF2 16
#define KT3 8

__global__ void prep_w1(const float* __restrict__ W1, const float* __restrict__ cw,
                        __bf16* __restrict__ w1s) {
  int gid  = blockIdx.x * 256 + threadIdx.x;   // 51200 threads
  int lane = gid & 63;
  int slot = gid >> 6;                         // 0..799
  int t = slot >> 5;
  int f = slot & 31;
  int kbase = t * 32 + ((lane >> 4) << 3);
  int n = f * 16 + (lane & 15);
  float c[9];
#pragma unroll
  for (int i = 0; i < 9; ++i) c[i] = cw[i];
  bf16x8 v;
#pragma unroll
  for (int e = 0; e < 8; ++e) {
    int k = kbase + e;
    float acc = 0.f;
    if (k < 784 && n < 500) {
      int pi = k / 28, pj = k % 28;
#pragma unroll
      for (int dr = 0; dr < 3; ++dr) {
        int r = pi - dr;
        if (r < 0 || r >= 26) continue;
#pragma unroll
        for (int dc = 0; dc < 3; ++dc) {
          int cc = pj - dc;
          if (cc < 0 || cc >= 26) continue;
          acc += c[dr * 3 + dc] * W1[(size_t)(r * 26 + cc) * 500 + n];
        }
      }
    }
    v[e] = (__bf16)acc;
  }
  *(bf16x8*)(w1s + (size_t)(slot * 64 + lane) * 8) = v;
}

__global__ void prep_w2(const float* __restrict__ W2, __bf16* __restrict__ w2s) {
  int gid  = blockIdx.x * 256 + threadIdx.x;
  int lane = gid & 63;
  int slot = gid >> 6;
  int t = slot >> 4;
  int f = slot & 15;
  int kbase = t * 32 + ((lane >> 4) << 3);
  int n = f * 16 + (lane & 15);
  bf16x8 v;
#pragma unroll
  for (int e = 0; e < 8; ++e) {
    int k = kbase + e;
    float val = (k < 500 && n < 200) ? W2[(size_t)k * 200 + n] : 0.f;
    v[e] = (__bf16)val;
  }
  *(bf16x8*)(w2s + (size_t)(slot * 64 + lane) * 8) = v;
}

__global__ void prep_w3(const float* __restrict__ W3, __bf16* __restrict__ w3s) {
  int gid  = blockIdx.x * 256 + threadIdx.x;
  int lane = gid & 63;
  int t    = gid >> 6;
  int kbase = t * 32 + ((lane >> 4) << 3);
  int n = lane & 15;
  bf16x8 v;
#pragma unroll
  for (int e = 0; e < 8; ++e) {
    int k = kbase + e;
    float val = (k < 200 && n < 10) ? W3[(size_t)k * 10 + n] : 0.f;
    v[e] = (__bf16)val;
  }
  *(bf16x8*)(w3s + (size_t)(t * 64 + lane) * 8) = v;
}

// ---- kernel 1: h1f = relu(x @ W1eff + b1) in A-fragment order ----
// block = 64 rows x 256 cols (n-half), 4 waves, wave = 64r x 64c (acc[4][4] = 64 AGPR).
// x staged via registers as bf16 (T14) into 2x4KB LDS double buffer; one lgkm-only
// barrier per k-tile (vmem loads in flight across barriers, T4). 3 waves/SIMD target.
__global__ __launch_bounds__(256, 3) void gemm1(
    const float* __restrict__ x,
    const __bf16* __restrict__ w1s,
    const float* __restrict__ b1,
    __bf16* __restrict__ h1f,
    int mtiles)
{
  __shared__ __align__(16) char xsm[2 * 4096];   // bf16 x-tile double buffer
  __shared__ __align__(16) char ts[16 * 528];    // transpose stage, padded stride
  __shared__ float sb1[256];

  const int tid  = threadIdx.x;
  const int lane = tid & 63;
  const int w    = tid >> 6;
  const int lrow = lane & 15;
  const int lgrp = lane >> 4;
  const int bid  = blockIdx.x;
  const int nh   = (bid >= mtiles) ? 1 : 0;
  const int mt   = nh ? bid - mtiles : bid;
  const int brow = mt * 64;
  const int xr   = tid >> 2;
  const int xq   = tid & 3;

  { int n = nh * 256 + tid; sb1[tid] = (n < 500) ? b1[n] : 0.f; }

  const f32x4 FZ = {0.f, 0.f, 0.f, 0.f};
  f32x4 acc[4][4];
#pragma unroll
  for (int m = 0; m < 4; ++m)
#pragma unroll
    for (int f = 0; f < 4; ++f) acc[m][f] = FZ;

  // B-frag base: slot = t*32 + nh*16 + w*4 + f
  const bf16x8* w1p   = (const bf16x8*)w1s + ((size_t)(nh * 16 + w * 4) * 64 + lane);
  const float*  xbase = x + (size_t)(brow + xr) * 784;
  const int     xoff  = xr * 64 + ((xq ^ (xr & 3)) << 4);

  auto gload = [&](int t, f32x4 (&g)[2]) {
    int gk = t * 32 + xq * 8;
    if (gk > 776) gk = 776;     // k>=784 garbage multiplies zero B rows
    const float* p = xbase + gk;
    g[0] = *(const f32x4*)p;
    g[1] = *(const f32x4*)(p + 4);
  };
  auto cwrite = [&](f32x4 (&g)[2], int bw) {
    bf16x8 v;
#pragma unroll
    for (int e = 0; e < 4; ++e) { v[e] = (__bf16)g[0][e]; v[e + 4] = (__bf16)g[1][e]; }
    *(bf16x8*)(xsm + bw + xoff) = v;
  };

  f32x4  grA[2], grB[2];
  bf16x8 bA[4], bB[4];

  auto body1 = [&](int t, bf16x8 (&bc)[4], bf16x8 (&bn)[4],
                   f32x4 (&gc)[2], f32x4 (&gl)[2], int bufR, int bufW) {
    bf16x8 afr[4];
#pragma unroll
    for (int m = 0; m < 4; ++m) {
      int r = m * 16 + lrow;
      afr[m] = *(const bf16x8*)(xsm + bufR + r * 64 + ((lgrp ^ (r & 3)) << 4));
    }
#pragma unroll
    for (int f = 0; f < 4; ++f) bn[f] = w1p[(size_t)((t + 1) * NF1 + f) * 64];
    gload(t + 2 > 24 ? 24 : t + 2, gl);
    cwrite(gc, bufW);

    __builtin_amdgcn_s_setprio(1);
#pragma unroll
    for (int f = 0; f < 4; ++f)
#pragma unroll
      for (int m = 0; m < 4; ++m)
        acc[m][f] = __builtin_amdgcn_mfma_f32_16x16x32_bf16(afr[m], bc[f], acc[m][f], 0, 0, 0);
    __builtin_amdgcn_s_setprio(0);

    asm volatile("s_waitcnt lgkmcnt(0)\n\ts_barrier" ::: "memory");
  };

  gload(0, grA);
#pragma unroll
  for (int f = 0; f < 4; ++f) bA[f] = w1p[(size_t)f * 64];
  gload(1, grB);
  cwrite(grA, 0);
  asm volatile("s_waitcnt lgkmcnt(0)\n\ts_barrier" ::: "memory");

  for (int t = 0; t < 24; t += 2) {
    body1(t,     bA, bB, grB, grA, 0,    4096);
    body1(t + 1, bB, bA, grA, grB, 4096, 0);
  }
  // tail tile 24
  {
    bf16x8 afr[4];
#pragma unroll
    for (int m = 0; m < 4; ++m) {
      int r = m * 16 + lrow;
      afr[m] = *(const bf16x8*)(xsm + r * 64 + ((lgrp ^ (r & 3)) << 4));
    }
    __builtin_amdgcn_s_setprio(1);
#pragma unroll
    for (int f = 0; f < 4; ++f)
#pragma unroll
      for (int m = 0; m < 4; ++m)
        acc[m][f] = __builtin_amdgcn_mfma_f32_16x16x32_bf16(afr[m], bA[f], acc[m][f], 0, 0, 0);
    __builtin_amdgcn_s_setprio(0);
  }
  asm volatile("s_waitcnt lgkmcnt(0)\n\ts_barrier" ::: "memory");   // xsm dead; ts safe

  // epilogue: per 16-row slab m: bias+relu -> ts[16][264] -> coalesced frag-order writeout
#pragma unroll
  for (int m = 0; m < 4; ++m) {
#pragma unroll
    for (int f = 0; f < 4; ++f) {
      int col = w * 64 + f * 16 + lrow;    // 0..255 within half
      float bias = sb1[col];
#pragma unroll
      for (int r = 0; r < 4; ++r) {
        int row = lgrp * 4 + r;            // 0..15
        float v = fmaxf(acc[m][f][r] + bias, 0.f);
        *(__bf16*)(ts + row * 528 + col * 2) = (__bf16)v;
      }
    }
    asm volatile("s_waitcnt lgkmcnt(0)\n\ts_barrier" ::: "memory");
    // copy out: slot s covers (ktl, lane2); 16B contiguous reads/writes
#pragma unroll
    for (int it = 0; it < 2; ++it) {
      int s    = it * 256 + tid;     // 0..511
      int ktl  = s >> 6;             // 0..7 (local k-tile)
      int ln   = s & 63;
      f32x4 v = *(const f32x4*)(ts + (ln & 15) * 528 + (ktl * 32 + (ln >> 4) * 8) * 2);
      *(f32x4*)((char*)h1f + (((size_t)(mt * 4 + m) * 16) + (nh * 8 + ktl)) * 1024 + ln * 16) = v;
    }
    asm volatile("s_waitcnt lgkmcnt(0) vmcnt(0)\n\ts_barrier" ::: "memory");
  }
}

// ---- kernel 2: layers 2+3. A from h1f (fragment order, coalesced), B from w2s.
// Barrier-free main loop; 64 rows/block, 4 waves, wave = 64r x 64c.
__global__ __launch_bounds__(256, 3) void gemm23(
    const __bf16* __restrict__ h1f,
    const __bf16* __restrict__ w2s, const __bf16* __restrict__ w3s,
    const float* __restrict__ b2, const float* __restrict__ b3,
    float* __restrict__ out)
{
  __shared__ __align__(16) char h2s[64 * 512];   // 32 KB swizzled
  __shared__ float sb2[256];

  const int tid  = threadIdx.x;
  const int lane = tid & 63;
  const int w    = tid >> 6;
  const int lrow = lane & 15;
  const int lgrp = lane >> 4;
  const int brow = blockIdx.x * 64;

  sb2[tid] = (tid < 200) ? b2[tid] : 0.f;

  const f32x4 FZ = {0.f, 0.f, 0.f, 0.f};
  f32x4 acc[4][4];
#pragma unroll
  for (int m = 0; m < 4; ++m)
#pragma unroll
    for (int f = 0; f < 4; ++f) acc[m][f] = FZ;

  // A frag(m,kt) = ap[(m*16+kt)*64]; B frag(kt,f) = w2p[(kt*16+f)*64]
  const bf16x8* ap  = (const bf16x8*)h1f + ((size_t)blockIdx.x * 4 * 16) * 64 + lane;
  const bf16x8* w2p = (const bf16x8*)w2s + ((size_t)(w * 4)) * 64 + lane;

  bf16x8 aP[4], aQ[4], bP[4], bQ[4];
#pragma unroll
  for (int m = 0; m < 4; ++m) aP[m] = ap[(size_t)(m * 16 + 0) * 64];
#pragma unroll
  for (int f = 0; f < 4; ++f) bP[f] = w2p[(size_t)(0 * NF2 + f) * 64];
#pragma unroll
  for (int m = 0; m < 4; ++m) aQ[m] = ap[(size_t)(m * 16 + 1) * 64];
#pragma unroll
  for (int f = 0; f < 4; ++f) bQ[f] = w2p[(size_t)(1 * NF2 + f) * 64];

  for (int kt = 0; kt < KT2; kt += 2) {
    __builtin_amdgcn_s_setprio(1);
#pragma unroll
    for (int f = 0; f < 4; ++f)
#pragma unroll
      for (int m = 0; m < 4; ++m)
        acc[m][f] = __builtin_amdgcn_mfma_f32_16x16x32_bf16(aP[m], bP[f], acc[m][f], 0, 0, 0);
    __builtin_amdgcn_s_setprio(0);
    {
      int ka = (kt + 2 < 16) ? kt + 2 : 15;          // clamp A (stay in h1f)
#pragma unroll
      for (int m = 0; m < 4; ++m) aP[m] = ap[(size_t)(m * 16 + ka) * 64];
#pragma unroll
      for (int f = 0; f < 4; ++f) bP[f] = w2p[(size_t)((kt + 2) * NF2 + f) * 64];  // kt=14 -> w3s region, harmless
    }
    __builtin_amdgcn_s_setprio(1);
#pragma unroll
    for (int f = 0; f < 4; ++f)
#pragma unroll
      for (int m = 0; m < 4; ++m)
        acc[m][f] = __builtin_amdgcn_mfma_f32_16x16x32_bf16(aQ[m], bQ[f], acc[m][f], 0, 0, 0);
    __builtin_amdgcn_s_setprio(0);
    {
      int ka = (kt + 3 < 16) ? kt + 3 : 15;
#pragma unroll
      for (int m = 0; m < 4; ++m) aQ[m] = ap[(size_t)(m * 16 + ka) * 64];
#pragma unroll
      for (int f = 0; f < 4; ++f) bQ[f] = w2p[(size_t)((kt + 3) * NF2 + f) * 64];
    }
  }

  __syncthreads();   // sb2 visible; h2s unwritten before here

  // epilogue 2 -> h2s (cols >= 200 exact zeros: acc==0, bias==0)
#pragma unroll
  for (int m = 0; m < 4; ++m) {
#pragma unroll
    for (int f = 0; f < 4; ++f) {
      int col = w * 64 + f * 16 + lrow;
      float bias = sb2[col];
#pragma unroll
      for (int r = 0; r < 4; ++r) {
        int row = m * 16 + lgrp * 4 + r;
        float v = fmaxf(acc[m][f][r] + bias, 0.f);
        int off = row * 512 + ((col * 2) ^ ((row & 7) << 4));
        *(__bf16*)(h2s + off) = (__bf16)v;
      }
    }
  }

  // preload ALL layer-3 B frags; ride across the lgkm-only barrier
  const bf16x8* w3p = (const bf16x8*)w3s + lane;
  bf16x8 w3f[8];
#pragma unroll
  for (int t = 0; t < KT3; ++t) w3f[t] = w3p[(size_t)t * 64];

  asm volatile("s_waitcnt lgkmcnt(0)\n\ts_barrier" ::: "memory");   // h2s visible

  // layer 3: wave w owns rows w*16..w*16+15
  {
    f32x4 a3 = FZ;
#pragma unroll
    for (int t = 0; t < KT3; ++t) {
      int row = w * 16 + lrow;
      int off = row * 512 + ((t * 64 + lgrp * 16) ^ ((row & 7) << 4));
      bf16x8 a = *(const bf16x8*)(h2s + off);
      a3 = __builtin_amdgcn_mfma_f32_16x16x32_bf16(a, w3f[t], a3, 0, 0, 0);
    }
    if (lrow < 10) {
      float bias = b3[lrow];
#pragma unroll
      for (int r = 0; r < 4; ++r)
        out[(size_t)(brow + w * 16 + lgrp * 4 + r) * 10 + lrow] = a3[r] + bias;
    }
  }
}

extern "C" void kernel_launch(void* const* d_in, const int* in_sizes, int n_in,
                              void* d_out, int out_size, void* d_ws, size_t ws_size,
                              hipStream_t stream) {
  const float* x  = (const float*)d_in[0];
  const float* cw = (const float*)d_in[1];
  const float* W1 = (const float*)d_in[2];
  const float* b1 = (const float*)d_in[3];
  const float* W2 = (const float*)d_in[4];
  const float* b2 = (const float*)d_in[5];
  const float* W3 = (const float*)d_in[6];
  const float* b3 = (const float*)d_in[7];
  float* out = (float*)d_out;

  __bf16* w1s = (__bf16*)d_ws;                      // 800 KB
  __bf16* w2s = w1s + (size_t)KT1 * NF1 * 64 * 8;   // 256 KB
  __bf16* w3s = w2s + (size_t)KT2 * NF2 * 64 * 8;   // 8 KB

  size_t woff  = ((size_t)KT1 * NF1 + KT2 * NF2 + KT3) * 64 * 8 * sizeof(__bf16);
  size_t h1off = (woff + 255) & ~(size_t)255;
  __bf16* h1f  = (__bf16*)((char*)d_ws + h1off);

  // chunk batch so h1f (1 KB per row) fits in remaining workspace
  size_t avail   = (ws_size > h1off) ? ws_size - h1off : 0;
  size_t maxrows = avail / 1024;
  int chunk = 65536;
  while ((size_t)chunk > maxrows && chunk > 64) chunk >>= 1;

  prep_w1<<<200, 256, 0, stream>>>(W1, cw, w1s);
  prep_w2<<<64, 256, 0, stream>>>(W2, w2s);
  prep_w3<<<2, 256, 0, stream>>>(W3, w3s);

  for (int r0 = 0; r0 < 65536; r0 += chunk) {
    int mt = chunk / 64;
    gemm1<<<mt * 2, 256, 0, stream>>>(x + (size_t)r0 * 784, w1s, b1, h1f, mt);
    gemm23<<<mt, 256, 0, stream>>>(h1f, w2s, w3s, b2, b3, out + (size_t)r0 * 10);
  }
}